// Round 11
// baseline (269.916 us; speedup 1.0000x reference)
//
#include <hip/hip_runtime.h>
#include <hip/hip_bf16.h>

#define N_NODES 100000
#define N0_ROWS 60000
#define N1_ROWS 40000
#define NE 1600000
#define HD 128
#define NB 782           // ceil(100000/128) buckets of 128 nodes
#define BSH 128          // nodes per bucket
#define EPB 6400         // edges per partition block
#define NBLK 250         // NE / EPB exactly

typedef __attribute__((ext_vector_type(8))) short short8;
typedef __attribute__((ext_vector_type(4))) float f32x4;
typedef __attribute__((ext_vector_type(2))) float f32x2;

__device__ __forceinline__ float bf16lo(unsigned v) { return __uint_as_float(v << 16); }
__device__ __forceinline__ float bf16hi(unsigned v) { return __uint_as_float(v & 0xFFFF0000u); }

__device__ __forceinline__ unsigned short f2bf_rne(float f) {
    unsigned u = __float_as_uint(f);
    return (unsigned short)((u + 0x7FFFu + ((u >> 16) & 1u)) >> 16);
}
__device__ __forceinline__ unsigned pack2_rne(float lo, float hi) {
    unsigned a = __float_as_uint(lo); a = (a + 0x7FFFu + ((a >> 16) & 1u)) >> 16;
    unsigned b = __float_as_uint(hi); b = (b + 0x7FFFu + ((b >> 16) & 1u)) & 0xFFFF0000u;
    return (a & 0xFFFFu) | b;
}
__device__ __forceinline__ float sigmoidf_(float v) { return 1.0f / (1.0f + __expf(-v)); }

// ---------------- fp8 e4m3fn conversion ----------------
#if defined(__has_builtin)
#if __has_builtin(__builtin_amdgcn_cvt_pk_fp8_f32) && __has_builtin(__builtin_amdgcn_cvt_pk_f32_fp8)
#define HAS_FP8_CVT 1
#endif
#endif

#ifdef HAS_FP8_CVT
__device__ __forceinline__ unsigned pack4_fp8(float c0, float c1, float c2, float c3) {
    int r = 0;
    r = __builtin_amdgcn_cvt_pk_fp8_f32(c0, c1, r, false);
    r = __builtin_amdgcn_cvt_pk_fp8_f32(c2, c3, r, true);
    return (unsigned)r;
}
template <bool HI>
__device__ __forceinline__ f32x2 unpack2_fp8(unsigned u) {
    return __builtin_amdgcn_cvt_pk_f32_fp8((int)u, HI);   // word-select is a literal
}
#else
__device__ __forceinline__ unsigned enc1_fp8(float f) {
    f = fminf(448.f, fmaxf(-448.f, f));
    float a = fabsf(f);
    unsigned s = (__float_as_uint(f) >> 31) << 7;
    if (a >= 0.015625f) {
        unsigned u = __float_as_uint(a);
        u += 0x7FFFFu + ((u >> 20) & 1u);
        int E = (int)((u >> 23) & 255) - 120;
        unsigned m3 = (u >> 20) & 7;
        if (E > 15) { E = 15; m3 = 6; }
        return s | ((unsigned)E << 3) | m3;
    } else {
        int q = (int)rintf(a * 512.f);
        if (q >= 8) return s | (1u << 3);
        return s | (unsigned)q;
    }
}
__device__ __forceinline__ unsigned pack4_fp8(float c0, float c1, float c2, float c3) {
    return enc1_fp8(c0) | (enc1_fp8(c1) << 8) | (enc1_fp8(c2) << 16) | (enc1_fp8(c3) << 24);
}
__device__ __forceinline__ float dec1_fp8(unsigned b) {
    unsigned s = (b >> 7) & 1, e = (b >> 3) & 15, m = b & 7;
    float v = e ? ldexpf((float)(8 + m), (int)e - 10) : ldexpf((float)m, -9);
    return s ? -v : v;
}
template <bool HI>
__device__ __forceinline__ f32x2 unpack2_fp8(unsigned u) {
    unsigned x = HI ? (u >> 16) : u;
    f32x2 r;
    r[0] = dec1_fp8(x & 0xFFu);
    r[1] = dec1_fp8((x >> 8) & 0xFFu);
    return r;
}
#endif

// ============ CSR pass A + bucket totals + weight prep (one launch) ============
__global__ __launch_bounds__(256) void k_phist_prep(const int* __restrict__ dst,
                                                    int* __restrict__ cnt,
                                                    int* __restrict__ bcnt,
                                                    const float* __restrict__ W0, unsigned short* __restrict__ T0,
                                                    const float* __restrict__ W1, unsigned short* __restrict__ T1,
                                                    const float* __restrict__ W2, unsigned short* __restrict__ T2,
                                                    const float* __restrict__ W3, unsigned short* __restrict__ T3,
                                                    const float* __restrict__ W4, unsigned short* __restrict__ T4) {
    int blk = blockIdx.x;
    if (blk < NBLK) {
        __shared__ int h[NB];
        for (int i = threadIdx.x; i < NB; i += 256) h[i] = 0;
        __syncthreads();
        int e0 = blk * EPB;
        for (int e = e0 + threadIdx.x; e < e0 + EPB; e += 256)
            atomicAdd(&h[dst[e] >> 7], 1);
        __syncthreads();
        for (int i = threadIdx.x; i < NB; i += 256) {
            int v = h[i];
            cnt[i * NBLK + blk] = v;
            if (v) atomicAdd(&bcnt[i], v);
        }
    } else {
        int gid = (blk - NBLK) * 256 + threadIdx.x;
        int stride = (gridDim.x - NBLK) * 256;
        const int S0 = 512 * 128, S1 = 256 * 128, S2 = 128 * 128, S3 = 128 * 128, S4 = 128 * 16;
        const int E1 = S0 + S1, E2 = E1 + S2, E3 = E2 + S3, E4 = E3 + S4;
        for (int i = gid; i < E4; i += stride) {
            if (i < S0) {
                int n = i / 512, k = i - n * 512;
                T0[i] = f2bf_rne(W0[k * 128 + n]);
            } else if (i < E1) {
                int j = i - S0; int n = j / 256, k = j - n * 256;
                T1[j] = f2bf_rne(W1[k * 128 + n]);
            } else if (i < E2) {
                int j = i - E1; int n = j / 128, k = j - n * 128;
                T2[j] = f2bf_rne(W2[k * 128 + n]);
            } else if (i < E3) {
                int j = i - E2; int n = j / 128, k = j - n * 128;
                T3[j] = f2bf_rne(W3[k * 128 + n]);
            } else {
                int j = i - E3; int n = j / 128, k = j - n * 128;
                T4[j] = f2bf_rne(W4[k * 16 + n]);
            }
        }
    }
}

// ============ merged column-scan (blocks 0..NB-1) + bucket-offset scan (block NB) ============
__global__ __launch_bounds__(64) void k_cbscan(int* __restrict__ cnt,
                                               const int* __restrict__ bcnt,
                                               int* __restrict__ boff,
                                               int* __restrict__ rowptr) {
    int lane = threadIdx.x & 63;
    if (blockIdx.x < NB) {
        int b = blockIdx.x;
        int* col = cnt + (size_t)b * NBLK;
        int carry = 0;
        for (int base = 0; base < NBLK; base += 64) {
            int i = base + lane;
            int v = (i < NBLK) ? col[i] : 0;
            int s = v;
            #pragma unroll
            for (int off = 1; off < 64; off <<= 1) {
                int t = __shfl_up(s, off);
                if (lane >= off) s += t;
            }
            if (i < NBLK) col[i] = carry + s - v;
            carry += __shfl(s, 63);
        }
    } else {
        const int CH = (NB + 63) / 64;   // 13
        int base = lane * CH;
        int t = 0;
        for (int c = 0; c < CH; ++c) {
            int i = base + c;
            t += (i < NB) ? bcnt[i] : 0;
        }
        int s = t;
        #pragma unroll
        for (int off = 1; off < 64; off <<= 1) {
            int u = __shfl_up(s, off);
            if (lane >= off) s += u;
        }
        int running = s - t;
        for (int c = 0; c < CH; ++c) {
            int i = base + c;
            if (i < NB) {
                boff[i] = running;
                running += bcnt[i];
            }
        }
        if (lane == 0) { boff[NB] = NE; rowptr[N_NODES] = NE; }
    }
}

__global__ __launch_bounds__(256) void k_pplace(const int* __restrict__ src,
                                                const int* __restrict__ dst,
                                                const int* __restrict__ boff,
                                                const int* __restrict__ cnt,
                                                unsigned* __restrict__ ebuf) {
    __shared__ int h[NB];
    int blk = blockIdx.x;
    for (int i = threadIdx.x; i < NB; i += 256) h[i] = cnt[i * NBLK + blk];
    __syncthreads();
    int e0 = blk * EPB;
    for (int e = e0 + threadIdx.x; e < e0 + EPB; e += 256) {
        int d = dst[e];
        int b = d >> 7;
        int pos = atomicAdd(&h[b], 1);
        ebuf[boff[b] + pos] = ((unsigned)(d & 127) << 17) | (unsigned)src[e];
    }
}

__global__ __launch_bounds__(256) void k_bplace(const unsigned* __restrict__ ebuf,
                                                const int* __restrict__ boff,
                                                int* __restrict__ rowptr,
                                                float* __restrict__ invd,
                                                int* __restrict__ eidx) {
    __shared__ int cnt[BSH], off[BSH], lcnt[BSH];
    int b = blockIdx.x, tid = threadIdx.x;
    int e0 = boff[b], e1 = boff[b + 1];
    for (int i = tid; i < BSH; i += 256) { cnt[i] = 0; lcnt[i] = 0; }
    __syncthreads();
    for (int e = e0 + tid; e < e1; e += 256)
        atomicAdd(&cnt[ebuf[e] >> 17], 1);
    __syncthreads();
    if (tid < 64) {
        int lane = tid;
        int c0 = cnt[2 * lane], c1 = cnt[2 * lane + 1];
        int t = c0 + c1, s = t;
        #pragma unroll
        for (int o = 1; o < 64; o <<= 1) {
            int u = __shfl_up(s, o);
            if (lane >= o) s += u;
        }
        int excl = s - t;
        off[2 * lane] = excl;
        off[2 * lane + 1] = excl + c0;
    }
    __syncthreads();
    for (int i = tid; i < BSH; i += 256) {
        int node = b * BSH + i;
        if (node < N_NODES) {
            rowptr[node] = e0 + off[i];
            invd[node] = 1.0f / fmaxf((float)cnt[i], 1.0f);
        }
    }
    for (int e = e0 + tid; e < e1; e += 256) {
        unsigned ent = ebuf[e];
        int d = ent >> 17;
        int pos = e0 + off[d] + atomicAdd(&lcnt[d], 1);
        eidx[pos] = (int)(ent & 0x1FFFFu);
    }
}

// ============ fused projection: z1 = (feat @ Wfc + bfc) @ Wg0, bf16 + fp8 ============
// 512 threads (8 waves), tile = 16 rows; register-prefetch of next tile's A.
// VGPR=64 -> 4 blocks/CU resident; grid supplies 4/CU (1024 blocks).
template <int K>
__global__ __launch_bounds__(512, 4) void k_proj_fused(const float* __restrict__ feat,
                                                       const unsigned short* __restrict__ Wt,
                                                       const float* __restrict__ bias,
                                                       const unsigned short* __restrict__ Wg,
                                                       unsigned short* __restrict__ zout,
                                                       unsigned* __restrict__ z8out,
                                                       int ntiles, int row_off) {
    constexpr int KC = K / 32;
    constexpr int NSEG = K / 128;
    __shared__ unsigned short A_lds[16][K + 8];
    __shared__ unsigned short h_lds[16][HD + 8];

    const int tid = threadIdx.x;
    const int lane = tid & 63, w = tid >> 6;
    const int g = lane >> 4, r16 = lane & 15;
    const int col = w * 16 + r16;

    short8 fb[KC];
    #pragma unroll
    for (int kc = 0; kc < KC; ++kc)
        fb[kc] = *reinterpret_cast<const short8*>(Wt + (size_t)col * K + kc * 32 + g * 8);
    short8 fbg[4];
    #pragma unroll
    for (int kc = 0; kc < 4; ++kc)
        fbg[kc] = *reinterpret_cast<const short8*>(Wg + (size_t)col * HD + kc * 32 + g * 8);
    const float bv = bias[col];

    const int srow = tid >> 5;                    // 0..15
    const int sseg = tid & 31;                    // 0..31

    float4 pre[NSEG];
    int tile = blockIdx.x;
    if (tile < ntiles) {
        const float4* rowp = reinterpret_cast<const float4*>(feat + (size_t)(tile * 16 + srow) * K);
        #pragma unroll
        for (int s = 0; s < NSEG; ++s) pre[s] = rowp[sseg + s * 32];
    }

    for (; tile < ntiles; tile += gridDim.x) {
        __syncthreads();   // prior readers of A_lds/h_lds done
        #pragma unroll
        for (int s = 0; s < NSEG; ++s) {
            unsigned lo = __builtin_amdgcn_perm(__float_as_uint(pre[s].y), __float_as_uint(pre[s].x), 0x07060302u);
            unsigned hi = __builtin_amdgcn_perm(__float_as_uint(pre[s].w), __float_as_uint(pre[s].z), 0x07060302u);
            *reinterpret_cast<uint2*>(&A_lds[srow][(sseg + s * 32) * 4]) = make_uint2(lo, hi);
        }
        __syncthreads();
        // issue next tile's loads; they retire under the MFMA/epilogue below
        int nt = tile + gridDim.x;
        if (nt < ntiles) {
            const float4* rowp = reinterpret_cast<const float4*>(feat + (size_t)(nt * 16 + srow) * K);
            #pragma unroll
            for (int s = 0; s < NSEG; ++s) pre[s] = rowp[sseg + s * 32];
        }
        f32x4 acc = {0.f, 0.f, 0.f, 0.f};
        #pragma unroll
        for (int kc = 0; kc < KC; ++kc) {
            short8 fa = *reinterpret_cast<const short8*>(&A_lds[r16][kc * 32 + g * 8]);
            acc = __builtin_amdgcn_mfma_f32_16x16x32_bf16(fa, fb[kc], acc, 0, 0, 0);
        }
        // stage h0 = acc + bias (bf16) to LDS
        #pragma unroll
        for (int r = 0; r < 4; ++r)
            h_lds[g * 4 + r][col] = f2bf_rne(acc[r] + bv);
        __syncthreads();
        // z1 tile = h0 @ Wg0
        f32x4 accz = {0.f, 0.f, 0.f, 0.f};
        #pragma unroll
        for (int kc = 0; kc < 4; ++kc) {
            short8 fa = *reinterpret_cast<const short8*>(&h_lds[r16][kc * 32 + g * 8]);
            accz = __builtin_amdgcn_mfma_f32_16x16x32_bf16(fa, fbg[kc], accz, 0, 0, 0);
        }
        #pragma unroll
        for (int r = 0; r < 4; ++r) {
            size_t orow = (size_t)(row_off + tile * 16 + g * 4 + r);
            zout[orow * HD + col] = f2bf_rne(accz[r]);
        }
        // restage z1 tile to LDS, pack fp8 copy
        __syncthreads();
        #pragma unroll
        for (int r = 0; r < 4; ++r)
            h_lds[g * 4 + r][col] = f2bf_rne(accz[r]);
        __syncthreads();
        {
            int c4 = sseg * 4;
            unsigned p = pack4_fp8(
                bf16lo((unsigned)h_lds[srow][c4])     ,
                bf16lo((unsigned)h_lds[srow][c4 + 1]) ,
                bf16lo((unsigned)h_lds[srow][c4 + 2]) ,
                bf16lo((unsigned)h_lds[srow][c4 + 3]) );
            z8out[(size_t)(row_off + tile * 16 + srow) * 32 + sseg] = p;
        }
    }
}

// ============ pure GEMM: z = h @ W (128->128), bf16 + fp8 out ============
__global__ __launch_bounds__(256, 4) void k_z_gemm(const unsigned short* __restrict__ x,
                                                   const unsigned short* __restrict__ Wt,
                                                   unsigned short* __restrict__ zout,
                                                   unsigned* __restrict__ z8out) {
    __shared__ unsigned short h_lds[16][HD + 8];
    const int lane = threadIdx.x & 63, wid = threadIdx.x >> 6;
    const int g = lane >> 4, r16 = lane & 15;
    const int colbase = wid * 32;
    const int prow = threadIdx.x >> 4;     // 0..15
    const int pseg = threadIdx.x & 15;     // 0..15

    short8 fb[2][4];
    #pragma unroll
    for (int nt = 0; nt < 2; ++nt) {
        int n = colbase + nt * 16 + r16;
        #pragma unroll
        for (int kc = 0; kc < 4; ++kc)
            fb[nt][kc] = *reinterpret_cast<const short8*>(Wt + (size_t)n * HD + kc * 32 + g * 8);
    }

    const int ntiles = N_NODES / 16;  // 6250
    for (int tile = blockIdx.x; tile < ntiles; tile += gridDim.x) {
        const unsigned short* ap = x + (size_t)(tile * 16 + r16) * HD;
        f32x4 acc0 = {0.f, 0.f, 0.f, 0.f};
        f32x4 acc1 = {0.f, 0.f, 0.f, 0.f};
        #pragma unroll
        for (int kc = 0; kc < 4; ++kc) {
            short8 fa = *reinterpret_cast<const short8*>(ap + kc * 32 + g * 8);
            acc0 = __builtin_amdgcn_mfma_f32_16x16x32_bf16(fa, fb[0][kc], acc0, 0, 0, 0);
            acc1 = __builtin_amdgcn_mfma_f32_16x16x32_bf16(fa, fb[1][kc], acc1, 0, 0, 0);
        }
        __syncthreads();   // protect h_lds from previous iteration's packers
        #pragma unroll
        for (int r = 0; r < 4; ++r) {
            size_t orow = (size_t)(tile * 16 + g * 4 + r);
            unsigned short zb0 = f2bf_rne(acc0[r]);
            unsigned short zb1 = f2bf_rne(acc1[r]);
            zout[orow * HD + colbase + r16]      = zb0;
            zout[orow * HD + colbase + 16 + r16] = zb1;
            h_lds[g * 4 + r][colbase + r16]      = zb0;
            h_lds[g * 4 + r][colbase + 16 + r16] = zb1;
        }
        __syncthreads();
        {
            int c8 = pseg * 8;
            unsigned p0 = pack4_fp8(
                bf16lo((unsigned)h_lds[prow][c8])     ,
                bf16lo((unsigned)h_lds[prow][c8 + 1]) ,
                bf16lo((unsigned)h_lds[prow][c8 + 2]) ,
                bf16lo((unsigned)h_lds[prow][c8 + 3]) );
            unsigned p1 = pack4_fp8(
                bf16lo((unsigned)h_lds[prow][c8 + 4]) ,
                bf16lo((unsigned)h_lds[prow][c8 + 5]) ,
                bf16lo((unsigned)h_lds[prow][c8 + 6]) ,
                bf16lo((unsigned)h_lds[prow][c8 + 7]) );
            *reinterpret_cast<uint2*>(&z8out[(size_t)(tile * 16 + prow) * 32 + pseg * 2]) =
                make_uint2(p0, p1);
        }
    }
}

// ============ aggregate: h = sigmoid(z_self(bf16) + invd*sum_neigh(fp8) + b) ============
// 2 nodes per wave: 32-lane half per node, u32/lane = 4 channels.
__global__ __launch_bounds__(256, 4) void k_aggz8(const unsigned short* __restrict__ z,
                                                  const unsigned* __restrict__ z8,
                                                  const int* __restrict__ rowptr,
                                                  const int* __restrict__ eidx,
                                                  const float* __restrict__ invd,
                                                  const float* __restrict__ bias,
                                                  unsigned short* __restrict__ hout) {
    const uint2* zp2 = reinterpret_cast<const uint2*>(z);
    uint2* hp2 = reinterpret_cast<uint2*>(hout);
    const int lane = threadIdx.x & 63, wid = threadIdx.x >> 6;
    const int half = lane >> 5, l32 = lane & 31;
    const float4 bvec = *reinterpret_cast<const float4*>(&bias[4 * l32]);
    const int npairs = N_NODES / 2;   // 50000
    int nwaves = gridDim.x * 4;
    for (int pair = blockIdx.x * 4 + wid; pair < npairs; pair += nwaves) {
        int node = pair * 2 + half;
        int rp0 = rowptr[node], rp1 = rowptr[node + 1];
        float a0 = 0.f, a1 = 0.f, a2 = 0.f, a3 = 0.f;
        for (int base = rp0; base < rp1; base += 32) {
            int m = rp1 - base; if (m > 32) m = 32;
            int idx = (l32 < m) ? eidx[base + l32] : 0;
            int t = 0;
            for (; t + 4 <= m; t += 4) {
                int j0 = __shfl(idx, half * 32 + t);
                int j1 = __shfl(idx, half * 32 + t + 1);
                int j2 = __shfl(idx, half * 32 + t + 2);
                int j3 = __shfl(idx, half * 32 + t + 3);
                unsigned u0 = z8[(size_t)j0 * 32 + l32];
                unsigned u1 = z8[(size_t)j1 * 32 + l32];
                unsigned u2 = z8[(size_t)j2 * 32 + l32];
                unsigned u3 = z8[(size_t)j3 * 32 + l32];
                f32x2 p;
                p = unpack2_fp8<false>(u0); a0 += p[0]; a1 += p[1];
                p = unpack2_fp8<true >(u0); a2 += p[0]; a3 += p[1];
                p = unpack2_fp8<false>(u1); a0 += p[0]; a1 += p[1];
                p = unpack2_fp8<true >(u1); a2 += p[0]; a3 += p[1];
                p = unpack2_fp8<false>(u2); a0 += p[0]; a1 += p[1];
                p = unpack2_fp8<true >(u2); a2 += p[0]; a3 += p[1];
                p = unpack2_fp8<false>(u3); a0 += p[0]; a1 += p[1];
                p = unpack2_fp8<true >(u3); a2 += p[0]; a3 += p[1];
            }
            for (; t < m; ++t) {
                int j = __shfl(idx, half * 32 + t);
                unsigned u = z8[(size_t)j * 32 + l32];
                f32x2 p;
                p = unpack2_fp8<false>(u); a0 += p[0]; a1 += p[1];
                p = unpack2_fp8<true >(u); a2 += p[0]; a3 += p[1];
            }
        }
        uint2 sv = zp2[(size_t)node * 32 + l32];
        float s = invd[node];
        float o0 = sigmoidf_(bf16lo(sv.x) + s * a0 + bvec.x);
        float o1 = sigmoidf_(bf16hi(sv.x) + s * a1 + bvec.y);
        float o2 = sigmoidf_(bf16lo(sv.y) + s * a2 + bvec.z);
        float o3 = sigmoidf_(bf16hi(sv.y) + s * a3 + bvec.w);
        hp2[(size_t)node * 32 + l32] = make_uint2(pack2_rne(o0, o1), pack2_rne(o2, o3));
    }
}

// ============ z3 = x @ Wout (128->16), bf16 out, no bias ============
__global__ __launch_bounds__(256, 4) void k_zout_gemm(const unsigned short* __restrict__ x,
                                                      const unsigned short* __restrict__ Wt,
                                                      unsigned short* __restrict__ z3) {
    const int lane = threadIdx.x & 63, wid = threadIdx.x >> 6;
    const int g = lane >> 4, r16 = lane & 15;

    short8 fb[4];
    #pragma unroll
    for (int kc = 0; kc < 4; ++kc)
        fb[kc] = *reinterpret_cast<const short8*>(Wt + (size_t)r16 * HD + kc * 32 + g * 8);

    const int ntiles = N_NODES / 16;  // 6250
    for (int tile = blockIdx.x * 4 + wid; tile < ntiles; tile += gridDim.x * 4) {
        const unsigned short* ap = x + (size_t)(tile * 16 + r16) * HD;
        f32x4 acc = {0.f, 0.f, 0.f, 0.f};
        #pragma unroll
        for (int kc = 0; kc < 4; ++kc) {
            short8 fa = *reinterpret_cast<const short8*>(ap + kc * 32 + g * 8);
            acc = __builtin_amdgcn_mfma_f32_16x16x32_bf16(fa, fb[kc], acc, 0, 0, 0);
        }
        #pragma unroll
        for (int r = 0; r < 4; ++r)
            z3[(size_t)(tile * 16 + g * 4 + r) * 16 + r16] = f2bf_rne(acc[r]);
    }
}

// ============ aggregate z3 (16-wide) + bias + sigmoid -> out(f32) ============
__global__ __launch_bounds__(256, 4) void k_agg16(const unsigned short* __restrict__ z3,
                                                  const int* __restrict__ rowptr,
                                                  const int* __restrict__ eidx,
                                                  const float* __restrict__ invd,
                                                  const float* __restrict__ bias,
                                                  float* __restrict__ out) {
    const unsigned* zp = reinterpret_cast<const unsigned*>(z3);
    int lane = threadIdx.x & 63, wid = threadIdx.x >> 6;
    int grp = lane >> 3, sub = lane & 7;
    float blo = bias[2 * sub], bhi = bias[2 * sub + 1];
    int step = gridDim.x * 32;
    for (int nb = blockIdx.x * 32 + wid * 8; nb < N_NODES; nb += step) {
        int node = nb + grp;
        bool valid = node < N_NODES;
        int rp0 = valid ? rowptr[node] : 0;
        int rp1 = valid ? rowptr[node + 1] : 0;
        float a0 = 0.f, a1 = 0.f;
        for (int base = rp0; base < rp1; base += 8) {
            int m = rp1 - base; if (m > 8) m = 8;
            int idx = (sub < m) ? eidx[base + sub] : 0;
            #pragma unroll
            for (int t = 0; t < 8; ++t) {
                if (t < m) {
                    int j = __shfl(idx, (grp << 3) + t);
                    unsigned v = zp[(size_t)j * 8 + sub];
                    a0 += bf16lo(v); a1 += bf16hi(v);
                }
            }
        }
        if (valid) {
            unsigned zv = zp[(size_t)node * 8 + sub];
            float s = invd[node];
            out[(size_t)node * 16 + sub * 2]     = sigmoidf_(bf16lo(zv) + s * a0 + blo);
            out[(size_t)node * 16 + sub * 2 + 1] = sigmoidf_(bf16hi(zv) + s * a1 + bhi);
        }
    }
}

extern "C" void kernel_launch(void* const* d_in, const int* in_sizes, int n_in,
                              void* d_out, int out_size, void* d_ws, size_t ws_size,
                              hipStream_t stream) {
    const float* feat0 = (const float*)d_in[0];
    const float* feat1 = (const float*)d_in[1];
    const int*   src   = (const int*)d_in[2];
    const int*   dst   = (const int*)d_in[3];
    const float* Wfc0  = (const float*)d_in[4];
    const float* bfc0  = (const float*)d_in[5];
    const float* Wfc1  = (const float*)d_in[6];
    const float* bfc1  = (const float*)d_in[7];
    const float* Wg0   = (const float*)d_in[8];
    const float* bg0   = (const float*)d_in[9];
    const float* Wg1   = (const float*)d_in[10];
    const float* bg1   = (const float*)d_in[11];
    const float* Wout  = (const float*)d_in[12];
    const float* bout  = (const float*)d_in[13];

    char* w = (char*)d_ws;
    auto alloc = [&](size_t bytes) {
        char* p = w;
        w += (bytes + 255) & ~(size_t)255;
        return p;
    };
    unsigned short* zA  = (unsigned short*)alloc((size_t)N_NODES * HD * 2);   // 25.6 MB
    unsigned short* zB  = (unsigned short*)alloc((size_t)N_NODES * HD * 2);   // 25.6 MB
    unsigned short* h   = (unsigned short*)alloc((size_t)N_NODES * HD * 2);   // 25.6 MB
    unsigned* z8A = (unsigned*)alloc((size_t)N_NODES * HD);                   // 12.8 MB
    unsigned* z8B = (unsigned*)alloc((size_t)N_NODES * HD);                   // 12.8 MB
    unsigned short* z3  = (unsigned short*)alloc((size_t)N_NODES * 16 * 2);   // 3.2 MB
    int*   rowptr = (int*)alloc((size_t)(N_NODES + 1) * 4);
    float* invd   = (float*)alloc((size_t)N_NODES * 4);
    int*   eidx   = (int*)alloc((size_t)NE * 4);                              // 6.4 MB
    unsigned* ebuf = (unsigned*)alloc((size_t)NE * 4);                        // 6.4 MB
    int*   cnt    = (int*)alloc((size_t)NB * NBLK * 4);                       // 0.78 MB
    int*   bcnt   = (int*)alloc((size_t)NB * 4);
    int*   boff   = (int*)alloc((size_t)(NB + 1) * 4);
    unsigned short* Wt_fc0 = (unsigned short*)alloc(512 * 128 * 2);
    unsigned short* Wt_fc1 = (unsigned short*)alloc(256 * 128 * 2);
    unsigned short* Wt_g0  = (unsigned short*)alloc(128 * 128 * 2);
    unsigned short* Wt_g1  = (unsigned short*)alloc(128 * 128 * 2);
    unsigned short* Wt_out = (unsigned short*)alloc(128 * 16 * 2);

    hipMemsetAsync(bcnt, 0, (size_t)NB * 4, stream);

    // CSR build (4 kernels) + weight prep fused into pass A
    k_phist_prep<<<NBLK + 70, 256, 0, stream>>>(dst, cnt, bcnt,
                                                Wfc0, Wt_fc0, Wfc1, Wt_fc1,
                                                Wg0, Wt_g0, Wg1, Wt_g1, Wout, Wt_out);
    k_cbscan<<<NB + 1, 64, 0, stream>>>(cnt, bcnt, boff, rowptr);
    k_pplace<<<NBLK, 256, 0, stream>>>(src, dst, boff, cnt, ebuf);
    k_bplace<<<NB, 256, 0, stream>>>(ebuf, boff, rowptr, invd, eidx);

    // fused projection + layer-1 GEMM (separate launches, 4 blocks/CU occupancy)
    k_proj_fused<512><<<1024, 512, 0, stream>>>(feat0, Wt_fc0, bfc0, Wt_g0, zA, z8A, N0_ROWS / 16, 0);
    k_proj_fused<256><<<1024, 512, 0, stream>>>(feat1, Wt_fc1, bfc1, Wt_g0, zA, z8A, N1_ROWS / 16, N0_ROWS);

    // layer 1 agg: h1 = sigmoid(z1 + mean(z1) + bg0)   [fp8 neighbor gather]
    k_aggz8<<<2048, 256, 0, stream>>>(zA, z8A, rowptr, eidx, invd, bg0, h);
    // layer 2 GEMM: z2 = h1 @ Wg1  (bf16 + fp8)
    k_z_gemm<<<2084, 256, 0, stream>>>(h, Wt_g1, zB, z8B);
    // layer 2 agg: h2 = sigmoid(z2 + mean(z2) + bg1)   [fp8 neighbor gather]
    k_aggz8<<<2048, 256, 0, stream>>>(zB, z8B, rowptr, eidx, invd, bg1, h);
    // layer 3 GEMM: z3 = h2 @ Wout (N x 16, bf16)
    k_zout_gemm<<<1563, 256, 0, stream>>>(h, Wt_out, z3);
    // final aggregation: out = sigmoid(z3 + mean(z3) + bout)
    k_agg16<<<2048, 256, 0, stream>>>(z3, rowptr, eidx, invd, bout, (float*)d_out);
}

// Round 12
// 250.427 us; speedup vs baseline: 1.0778x; 1.0778x over previous
//
#include <hip/hip_runtime.h>
#include <hip/hip_bf16.h>

#define N_NODES 100000
#define N0_ROWS 60000
#define N1_ROWS 40000
#define NE 1600000
#define HD 128
#define NB 782           // ceil(100000/128) buckets of 128 nodes
#define BSH 128          // nodes per bucket
#define EPB 6400         // edges per partition block
#define NBLK 250         // NE / EPB exactly

typedef __attribute__((ext_vector_type(8))) short short8;
typedef __attribute__((ext_vector_type(4))) float f32x4;
typedef __attribute__((ext_vector_type(2))) float f32x2;

__device__ __forceinline__ float bf16lo(unsigned v) { return __uint_as_float(v << 16); }
__device__ __forceinline__ float bf16hi(unsigned v) { return __uint_as_float(v & 0xFFFF0000u); }

__device__ __forceinline__ unsigned short f2bf_rne(float f) {
    unsigned u = __float_as_uint(f);
    return (unsigned short)((u + 0x7FFFu + ((u >> 16) & 1u)) >> 16);
}
__device__ __forceinline__ unsigned pack2_rne(float lo, float hi) {
    unsigned a = __float_as_uint(lo); a = (a + 0x7FFFu + ((a >> 16) & 1u)) >> 16;
    unsigned b = __float_as_uint(hi); b = (b + 0x7FFFu + ((b >> 16) & 1u)) & 0xFFFF0000u;
    return (a & 0xFFFFu) | b;
}
__device__ __forceinline__ float sigmoidf_(float v) { return 1.0f / (1.0f + __expf(-v)); }

// ---------------- fp8 e4m3fn conversion ----------------
#if defined(__has_builtin)
#if __has_builtin(__builtin_amdgcn_cvt_pk_fp8_f32) && __has_builtin(__builtin_amdgcn_cvt_pk_f32_fp8)
#define HAS_FP8_CVT 1
#endif
#endif

#ifdef HAS_FP8_CVT
__device__ __forceinline__ unsigned pack4_fp8(float c0, float c1, float c2, float c3) {
    int r = 0;
    r = __builtin_amdgcn_cvt_pk_fp8_f32(c0, c1, r, false);
    r = __builtin_amdgcn_cvt_pk_fp8_f32(c2, c3, r, true);
    return (unsigned)r;
}
template <bool HI>
__device__ __forceinline__ f32x2 unpack2_fp8(unsigned u) {
    return __builtin_amdgcn_cvt_pk_f32_fp8((int)u, HI);   // word-select is a literal
}
#else
__device__ __forceinline__ unsigned enc1_fp8(float f) {
    f = fminf(448.f, fmaxf(-448.f, f));
    float a = fabsf(f);
    unsigned s = (__float_as_uint(f) >> 31) << 7;
    if (a >= 0.015625f) {
        unsigned u = __float_as_uint(a);
        u += 0x7FFFFu + ((u >> 20) & 1u);
        int E = (int)((u >> 23) & 255) - 120;
        unsigned m3 = (u >> 20) & 7;
        if (E > 15) { E = 15; m3 = 6; }
        return s | ((unsigned)E << 3) | m3;
    } else {
        int q = (int)rintf(a * 512.f);
        if (q >= 8) return s | (1u << 3);
        return s | (unsigned)q;
    }
}
__device__ __forceinline__ unsigned pack4_fp8(float c0, float c1, float c2, float c3) {
    return enc1_fp8(c0) | (enc1_fp8(c1) << 8) | (enc1_fp8(c2) << 16) | (enc1_fp8(c3) << 24);
}
__device__ __forceinline__ float dec1_fp8(unsigned b) {
    unsigned s = (b >> 7) & 1, e = (b >> 3) & 15, m = b & 7;
    float v = e ? ldexpf((float)(8 + m), (int)e - 10) : ldexpf((float)m, -9);
    return s ? -v : v;
}
template <bool HI>
__device__ __forceinline__ f32x2 unpack2_fp8(unsigned u) {
    unsigned x = HI ? (u >> 16) : u;
    f32x2 r;
    r[0] = dec1_fp8(x & 0xFFu);
    r[1] = dec1_fp8((x >> 8) & 0xFFu);
    return r;
}
#endif

// ============ CSR pass A + weight prep (independent work, one launch) ============
__global__ __launch_bounds__(256) void k_phist_prep(const int* __restrict__ dst,
                                                    int* __restrict__ cnt,
                                                    const float* __restrict__ W0, unsigned short* __restrict__ T0,
                                                    const float* __restrict__ W1, unsigned short* __restrict__ T1,
                                                    const float* __restrict__ W2, unsigned short* __restrict__ T2,
                                                    const float* __restrict__ W3, unsigned short* __restrict__ T3,
                                                    const float* __restrict__ W4, unsigned short* __restrict__ T4) {
    int blk = blockIdx.x;
    if (blk < NBLK) {
        __shared__ int h[NB];
        for (int i = threadIdx.x; i < NB; i += 256) h[i] = 0;
        __syncthreads();
        int e0 = blk * EPB;
        for (int e = e0 + threadIdx.x; e < e0 + EPB; e += 256)
            atomicAdd(&h[dst[e] >> 7], 1);
        __syncthreads();
        for (int i = threadIdx.x; i < NB; i += 256)
            cnt[i * NBLK + blk] = h[i];
    } else {
        int gid = (blk - NBLK) * 256 + threadIdx.x;
        int stride = (gridDim.x - NBLK) * 256;
        const int S0 = 512 * 128, S1 = 256 * 128, S2 = 128 * 128, S3 = 128 * 128, S4 = 128 * 16;
        const int E1 = S0 + S1, E2 = E1 + S2, E3 = E2 + S3, E4 = E3 + S4;
        for (int i = gid; i < E4; i += stride) {
            if (i < S0) {
                int n = i / 512, k = i - n * 512;
                T0[i] = f2bf_rne(W0[k * 128 + n]);
            } else if (i < E1) {
                int j = i - S0; int n = j / 256, k = j - n * 256;
                T1[j] = f2bf_rne(W1[k * 128 + n]);
            } else if (i < E2) {
                int j = i - E1; int n = j / 128, k = j - n * 128;
                T2[j] = f2bf_rne(W2[k * 128 + n]);
            } else if (i < E3) {
                int j = i - E2; int n = j / 128, k = j - n * 128;
                T3[j] = f2bf_rne(W3[k * 128 + n]);
            } else {
                int j = i - E3; int n = j / 128, k = j - n * 128;
                T4[j] = f2bf_rne(W4[k * 16 + n]);
            }
        }
    }
}

__global__ __launch_bounds__(64) void k_colscan(int* __restrict__ cnt,
                                                int* __restrict__ bcnt) {
    int b = blockIdx.x, lane = threadIdx.x & 63;
    int* col = cnt + (size_t)b * NBLK;
    int carry = 0;
    for (int base = 0; base < NBLK; base += 64) {
        int i = base + lane;
        int v = (i < NBLK) ? col[i] : 0;
        int s = v;
        #pragma unroll
        for (int off = 1; off < 64; off <<= 1) {
            int t = __shfl_up(s, off);
            if (lane >= off) s += t;
        }
        if (i < NBLK) col[i] = carry + s - v;
        carry += __shfl(s, 63);
    }
    if (lane == 0) bcnt[b] = carry;
}

__global__ void k_bscan(const int* __restrict__ bcnt, int* __restrict__ boff,
                        int* __restrict__ rowptr) {
    int lane = threadIdx.x & 63;
    const int CH = (NB + 63) / 64;   // 13
    int base = lane * CH;
    int t = 0;
    for (int c = 0; c < CH; ++c) {
        int i = base + c;
        t += (i < NB) ? bcnt[i] : 0;
    }
    int s = t;
    #pragma unroll
    for (int off = 1; off < 64; off <<= 1) {
        int u = __shfl_up(s, off);
        if (lane >= off) s += u;
    }
    int running = s - t;
    for (int c = 0; c < CH; ++c) {
        int i = base + c;
        if (i < NB) {
            boff[i] = running;
            running += bcnt[i];
        }
    }
    if (lane == 0) { boff[NB] = NE; rowptr[N_NODES] = NE; }
}

__global__ __launch_bounds__(256) void k_pplace(const int* __restrict__ src,
                                                const int* __restrict__ dst,
                                                const int* __restrict__ boff,
                                                const int* __restrict__ cnt,
                                                unsigned* __restrict__ ebuf) {
    __shared__ int h[NB];
    int blk = blockIdx.x;
    for (int i = threadIdx.x; i < NB; i += 256) h[i] = cnt[i * NBLK + blk];
    __syncthreads();
    int e0 = blk * EPB;
    for (int e = e0 + threadIdx.x; e < e0 + EPB; e += 256) {
        int d = dst[e];
        int b = d >> 7;
        int pos = atomicAdd(&h[b], 1);
        ebuf[boff[b] + pos] = ((unsigned)(d & 127) << 17) | (unsigned)src[e];
    }
}

__global__ __launch_bounds__(256) void k_bplace(const unsigned* __restrict__ ebuf,
                                                const int* __restrict__ boff,
                                                int* __restrict__ rowptr,
                                                float* __restrict__ invd,
                                                int* __restrict__ eidx) {
    __shared__ int cnt[BSH], off[BSH], lcnt[BSH];
    int b = blockIdx.x, tid = threadIdx.x;
    int e0 = boff[b], e1 = boff[b + 1];
    for (int i = tid; i < BSH; i += 256) { cnt[i] = 0; lcnt[i] = 0; }
    __syncthreads();
    for (int e = e0 + tid; e < e1; e += 256)
        atomicAdd(&cnt[ebuf[e] >> 17], 1);
    __syncthreads();
    if (tid < 64) {
        int lane = tid;
        int c0 = cnt[2 * lane], c1 = cnt[2 * lane + 1];
        int t = c0 + c1, s = t;
        #pragma unroll
        for (int o = 1; o < 64; o <<= 1) {
            int u = __shfl_up(s, o);
            if (lane >= o) s += u;
        }
        int excl = s - t;
        off[2 * lane] = excl;
        off[2 * lane + 1] = excl + c0;
    }
    __syncthreads();
    for (int i = tid; i < BSH; i += 256) {
        int node = b * BSH + i;
        if (node < N_NODES) {
            rowptr[node] = e0 + off[i];
            invd[node] = 1.0f / fmaxf((float)cnt[i], 1.0f);
        }
    }
    for (int e = e0 + tid; e < e1; e += 256) {
        unsigned ent = ebuf[e];
        int d = ent >> 17;
        int pos = e0 + off[d] + atomicAdd(&lcnt[d], 1);
        eidx[pos] = (int)(ent & 0x1FFFFu);
    }
}

// ============ fused projection: z1 = (feat @ Wfc + bfc) @ Wg0, bf16 + fp8 ============
// 512 threads (8 waves), tile = 16 rows; register-prefetch of next tile's A.
template <int K>
__global__ __launch_bounds__(512, 4) void k_proj_fused(const float* __restrict__ feat,
                                                       const unsigned short* __restrict__ Wt,
                                                       const float* __restrict__ bias,
                                                       const unsigned short* __restrict__ Wg,
                                                       unsigned short* __restrict__ zout,
                                                       unsigned* __restrict__ z8out,
                                                       int ntiles, int row_off) {
    constexpr int KC = K / 32;
    constexpr int NSEG = K / 128;
    __shared__ unsigned short A_lds[16][K + 8];
    __shared__ unsigned short h_lds[16][HD + 8];

    const int tid = threadIdx.x;
    const int lane = tid & 63, w = tid >> 6;
    const int g = lane >> 4, r16 = lane & 15;
    const int col = w * 16 + r16;

    short8 fb[KC];
    #pragma unroll
    for (int kc = 0; kc < KC; ++kc)
        fb[kc] = *reinterpret_cast<const short8*>(Wt + (size_t)col * K + kc * 32 + g * 8);
    short8 fbg[4];
    #pragma unroll
    for (int kc = 0; kc < 4; ++kc)
        fbg[kc] = *reinterpret_cast<const short8*>(Wg + (size_t)col * HD + kc * 32 + g * 8);
    const float bv = bias[col];

    const int srow = tid >> 5;                    // 0..15
    const int sseg = tid & 31;                    // 0..31

    float4 pre[NSEG];
    int tile = blockIdx.x;
    if (tile < ntiles) {
        const float4* rowp = reinterpret_cast<const float4*>(feat + (size_t)(tile * 16 + srow) * K);
        #pragma unroll
        for (int s = 0; s < NSEG; ++s) pre[s] = rowp[sseg + s * 32];
    }

    for (; tile < ntiles; tile += gridDim.x) {
        __syncthreads();   // prior readers of A_lds/h_lds done
        #pragma unroll
        for (int s = 0; s < NSEG; ++s) {
            unsigned lo = __builtin_amdgcn_perm(__float_as_uint(pre[s].y), __float_as_uint(pre[s].x), 0x07060302u);
            unsigned hi = __builtin_amdgcn_perm(__float_as_uint(pre[s].w), __float_as_uint(pre[s].z), 0x07060302u);
            *reinterpret_cast<uint2*>(&A_lds[srow][(sseg + s * 32) * 4]) = make_uint2(lo, hi);
        }
        __syncthreads();
        // issue next tile's loads; they retire under the MFMA/epilogue below
        int nt = tile + gridDim.x;
        if (nt < ntiles) {
            const float4* rowp = reinterpret_cast<const float4*>(feat + (size_t)(nt * 16 + srow) * K);
            #pragma unroll
            for (int s = 0; s < NSEG; ++s) pre[s] = rowp[sseg + s * 32];
        }
        f32x4 acc = {0.f, 0.f, 0.f, 0.f};
        #pragma unroll
        for (int kc = 0; kc < KC; ++kc) {
            short8 fa = *reinterpret_cast<const short8*>(&A_lds[r16][kc * 32 + g * 8]);
            acc = __builtin_amdgcn_mfma_f32_16x16x32_bf16(fa, fb[kc], acc, 0, 0, 0);
        }
        // stage h0 = acc + bias (bf16) to LDS
        #pragma unroll
        for (int r = 0; r < 4; ++r)
            h_lds[g * 4 + r][col] = f2bf_rne(acc[r] + bv);
        __syncthreads();
        // z1 tile = h0 @ Wg0
        f32x4 accz = {0.f, 0.f, 0.f, 0.f};
        #pragma unroll
        for (int kc = 0; kc < 4; ++kc) {
            short8 fa = *reinterpret_cast<const short8*>(&h_lds[r16][kc * 32 + g * 8]);
            accz = __builtin_amdgcn_mfma_f32_16x16x32_bf16(fa, fbg[kc], accz, 0, 0, 0);
        }
        #pragma unroll
        for (int r = 0; r < 4; ++r) {
            size_t orow = (size_t)(row_off + tile * 16 + g * 4 + r);
            zout[orow * HD + col] = f2bf_rne(accz[r]);
        }
        // restage z1 tile to LDS, pack fp8 copy
        __syncthreads();
        #pragma unroll
        for (int r = 0; r < 4; ++r)
            h_lds[g * 4 + r][col] = f2bf_rne(accz[r]);
        __syncthreads();
        {
            int c4 = sseg * 4;
            unsigned p = pack4_fp8(
                bf16lo((unsigned)h_lds[srow][c4])     ,
                bf16lo((unsigned)h_lds[srow][c4 + 1]) ,
                bf16lo((unsigned)h_lds[srow][c4 + 2]) ,
                bf16lo((unsigned)h_lds[srow][c4 + 3]) );
            z8out[(size_t)(row_off + tile * 16 + srow) * 32 + sseg] = p;
        }
    }
}

// ============ pure GEMM: z = h @ W (128->128), bf16 + fp8 out ============
__global__ __launch_bounds__(256, 4) void k_z_gemm(const unsigned short* __restrict__ x,
                                                   const unsigned short* __restrict__ Wt,
                                                   unsigned short* __restrict__ zout,
                                                   unsigned* __restrict__ z8out) {
    __shared__ unsigned short h_lds[16][HD + 8];
    const int lane = threadIdx.x & 63, wid = threadIdx.x >> 6;
    const int g = lane >> 4, r16 = lane & 15;
    const int colbase = wid * 32;
    const int prow = threadIdx.x >> 4;     // 0..15
    const int pseg = threadIdx.x & 15;     // 0..15

    short8 fb[2][4];
    #pragma unroll
    for (int nt = 0; nt < 2; ++nt) {
        int n = colbase + nt * 16 + r16;
        #pragma unroll
        for (int kc = 0; kc < 4; ++kc)
            fb[nt][kc] = *reinterpret_cast<const short8*>(Wt + (size_t)n * HD + kc * 32 + g * 8);
    }

    const int ntiles = N_NODES / 16;  // 6250
    for (int tile = blockIdx.x; tile < ntiles; tile += gridDim.x) {
        const unsigned short* ap = x + (size_t)(tile * 16 + r16) * HD;
        f32x4 acc0 = {0.f, 0.f, 0.f, 0.f};
        f32x4 acc1 = {0.f, 0.f, 0.f, 0.f};
        #pragma unroll
        for (int kc = 0; kc < 4; ++kc) {
            short8 fa = *reinterpret_cast<const short8*>(ap + kc * 32 + g * 8);
            acc0 = __builtin_amdgcn_mfma_f32_16x16x32_bf16(fa, fb[0][kc], acc0, 0, 0, 0);
            acc1 = __builtin_amdgcn_mfma_f32_16x16x32_bf16(fa, fb[1][kc], acc1, 0, 0, 0);
        }
        __syncthreads();   // protect h_lds from previous iteration's packers
        #pragma unroll
        for (int r = 0; r < 4; ++r) {
            size_t orow = (size_t)(tile * 16 + g * 4 + r);
            unsigned short zb0 = f2bf_rne(acc0[r]);
            unsigned short zb1 = f2bf_rne(acc1[r]);
            zout[orow * HD + colbase + r16]      = zb0;
            zout[orow * HD + colbase + 16 + r16] = zb1;
            h_lds[g * 4 + r][colbase + r16]      = zb0;
            h_lds[g * 4 + r][colbase + 16 + r16] = zb1;
        }
        __syncthreads();
        {
            int c8 = pseg * 8;
            unsigned p0 = pack4_fp8(
                bf16lo((unsigned)h_lds[prow][c8])     ,
                bf16lo((unsigned)h_lds[prow][c8 + 1]) ,
                bf16lo((unsigned)h_lds[prow][c8 + 2]) ,
                bf16lo((unsigned)h_lds[prow][c8 + 3]) );
            unsigned p1 = pack4_fp8(
                bf16lo((unsigned)h_lds[prow][c8 + 4]) ,
                bf16lo((unsigned)h_lds[prow][c8 + 5]) ,
                bf16lo((unsigned)h_lds[prow][c8 + 6]) ,
                bf16lo((unsigned)h_lds[prow][c8 + 7]) );
            *reinterpret_cast<uint2*>(&z8out[(size_t)(tile * 16 + prow) * 32 + pseg * 2]) =
                make_uint2(p0, p1);
        }
    }
}

// ============ aggregate: h = sigmoid(z_self(bf16) + invd*sum_neigh(fp8) + b) ============
// 2 nodes per wave: 32-lane half per node, u32/lane = 4 channels.
__global__ __launch_bounds__(256, 4) void k_aggz8(const unsigned short* __restrict__ z,
                                                  const unsigned* __restrict__ z8,
                                                  const int* __restrict__ rowptr,
                                                  const int* __restrict__ eidx,
                                                  const float* __restrict__ invd,
                                                  const float* __restrict__ bias,
                                                  unsigned short* __restrict__ hout) {
    const uint2* zp2 = reinterpret_cast<const uint2*>(z);
    uint2* hp2 = reinterpret_cast<uint2*>(hout);
    const int lane = threadIdx.x & 63, wid = threadIdx.x >> 6;
    const int half = lane >> 5, l32 = lane & 31;
    const float4 bvec = *reinterpret_cast<const float4*>(&bias[4 * l32]);
    const int npairs = N_NODES / 2;   // 50000
    int nwaves = gridDim.x * 4;
    for (int pair = blockIdx.x * 4 + wid; pair < npairs; pair += nwaves) {
        int node = pair * 2 + half;
        int rp0 = rowptr[node], rp1 = rowptr[node + 1];
        float a0 = 0.f, a1 = 0.f, a2 = 0.f, a3 = 0.f;
        for (int base = rp0; base < rp1; base += 32) {
            int m = rp1 - base; if (m > 32) m = 32;
            int idx = (l32 < m) ? eidx[base + l32] : 0;
            int t = 0;
            for (; t + 4 <= m; t += 4) {
                int j0 = __shfl(idx, half * 32 + t);
                int j1 = __shfl(idx, half * 32 + t + 1);
                int j2 = __shfl(idx, half * 32 + t + 2);
                int j3 = __shfl(idx, half * 32 + t + 3);
                unsigned u0 = z8[(size_t)j0 * 32 + l32];
                unsigned u1 = z8[(size_t)j1 * 32 + l32];
                unsigned u2 = z8[(size_t)j2 * 32 + l32];
                unsigned u3 = z8[(size_t)j3 * 32 + l32];
                f32x2 p;
                p = unpack2_fp8<false>(u0); a0 += p[0]; a1 += p[1];
                p = unpack2_fp8<true >(u0); a2 += p[0]; a3 += p[1];
                p = unpack2_fp8<false>(u1); a0 += p[0]; a1 += p[1];
                p = unpack2_fp8<true >(u1); a2 += p[0]; a3 += p[1];
                p = unpack2_fp8<false>(u2); a0 += p[0]; a1 += p[1];
                p = unpack2_fp8<true >(u2); a2 += p[0]; a3 += p[1];
                p = unpack2_fp8<false>(u3); a0 += p[0]; a1 += p[1];
                p = unpack2_fp8<true >(u3); a2 += p[0]; a3 += p[1];
            }
            for (; t < m; ++t) {
                int j = __shfl(idx, half * 32 + t);
                unsigned u = z8[(size_t)j * 32 + l32];
                f32x2 p;
                p = unpack2_fp8<false>(u); a0 += p[0]; a1 += p[1];
                p = unpack2_fp8<true >(u); a2 += p[0]; a3 += p[1];
            }
        }
        uint2 sv = zp2[(size_t)node * 32 + l32];
        float s = invd[node];
        float o0 = sigmoidf_(bf16lo(sv.x) + s * a0 + bvec.x);
        float o1 = sigmoidf_(bf16hi(sv.x) + s * a1 + bvec.y);
        float o2 = sigmoidf_(bf16lo(sv.y) + s * a2 + bvec.z);
        float o3 = sigmoidf_(bf16hi(sv.y) + s * a3 + bvec.w);
        hp2[(size_t)node * 32 + l32] = make_uint2(pack2_rne(o0, o1), pack2_rne(o2, o3));
    }
}

// ============ z3 = x @ Wout (128->16), bf16 out, no bias ============
__global__ __launch_bounds__(256, 4) void k_zout_gemm(const unsigned short* __restrict__ x,
                                                      const unsigned short* __restrict__ Wt,
                                                      unsigned short* __restrict__ z3) {
    const int lane = threadIdx.x & 63, wid = threadIdx.x >> 6;
    const int g = lane >> 4, r16 = lane & 15;

    short8 fb[4];
    #pragma unroll
    for (int kc = 0; kc < 4; ++kc)
        fb[kc] = *reinterpret_cast<const short8*>(Wt + (size_t)r16 * HD + kc * 32 + g * 8);

    const int ntiles = N_NODES / 16;  // 6250
    for (int tile = blockIdx.x * 4 + wid; tile < ntiles; tile += gridDim.x * 4) {
        const unsigned short* ap = x + (size_t)(tile * 16 + r16) * HD;
        f32x4 acc = {0.f, 0.f, 0.f, 0.f};
        #pragma unroll
        for (int kc = 0; kc < 4; ++kc) {
            short8 fa = *reinterpret_cast<const short8*>(ap + kc * 32 + g * 8);
            acc = __builtin_amdgcn_mfma_f32_16x16x32_bf16(fa, fb[kc], acc, 0, 0, 0);
        }
        #pragma unroll
        for (int r = 0; r < 4; ++r)
            z3[(size_t)(tile * 16 + g * 4 + r) * 16 + r16] = f2bf_rne(acc[r]);
    }
}

// ============ aggregate z3 (16-wide) + bias + sigmoid -> out(f32) ============
__global__ __launch_bounds__(256, 4) void k_agg16(const unsigned short* __restrict__ z3,
                                                  const int* __restrict__ rowptr,
                                                  const int* __restrict__ eidx,
                                                  const float* __restrict__ invd,
                                                  const float* __restrict__ bias,
                                                  float* __restrict__ out) {
    const unsigned* zp = reinterpret_cast<const unsigned*>(z3);
    int lane = threadIdx.x & 63, wid = threadIdx.x >> 6;
    int grp = lane >> 3, sub = lane & 7;
    float blo = bias[2 * sub], bhi = bias[2 * sub + 1];
    int step = gridDim.x * 32;
    for (int nb = blockIdx.x * 32 + wid * 8; nb < N_NODES; nb += step) {
        int node = nb + grp;
        bool valid = node < N_NODES;
        int rp0 = valid ? rowptr[node] : 0;
        int rp1 = valid ? rowptr[node + 1] : 0;
        float a0 = 0.f, a1 = 0.f;
        for (int base = rp0; base < rp1; base += 8) {
            int m = rp1 - base; if (m > 8) m = 8;
            int idx = (sub < m) ? eidx[base + sub] : 0;
            #pragma unroll
            for (int t = 0; t < 8; ++t) {
                if (t < m) {
                    int j = __shfl(idx, (grp << 3) + t);
                    unsigned v = zp[(size_t)j * 8 + sub];
                    a0 += bf16lo(v); a1 += bf16hi(v);
                }
            }
        }
        if (valid) {
            unsigned zv = zp[(size_t)node * 8 + sub];
            float s = invd[node];
            out[(size_t)node * 16 + sub * 2]     = sigmoidf_(bf16lo(zv) + s * a0 + blo);
            out[(size_t)node * 16 + sub * 2 + 1] = sigmoidf_(bf16hi(zv) + s * a1 + bhi);
        }
    }
}

extern "C" void kernel_launch(void* const* d_in, const int* in_sizes, int n_in,
                              void* d_out, int out_size, void* d_ws, size_t ws_size,
                              hipStream_t stream) {
    const float* feat0 = (const float*)d_in[0];
    const float* feat1 = (const float*)d_in[1];
    const int*   src   = (const int*)d_in[2];
    const int*   dst   = (const int*)d_in[3];
    const float* Wfc0  = (const float*)d_in[4];
    const float* bfc0  = (const float*)d_in[5];
    const float* Wfc1  = (const float*)d_in[6];
    const float* bfc1  = (const float*)d_in[7];
    const float* Wg0   = (const float*)d_in[8];
    const float* bg0   = (const float*)d_in[9];
    const float* Wg1   = (const float*)d_in[10];
    const float* bg1   = (const float*)d_in[11];
    const float* Wout  = (const float*)d_in[12];
    const float* bout  = (const float*)d_in[13];

    char* w = (char*)d_ws;
    auto alloc = [&](size_t bytes) {
        char* p = w;
        w += (bytes + 255) & ~(size_t)255;
        return p;
    };
    unsigned short* zA  = (unsigned short*)alloc((size_t)N_NODES * HD * 2);   // 25.6 MB
    unsigned short* zB  = (unsigned short*)alloc((size_t)N_NODES * HD * 2);   // 25.6 MB
    unsigned short* h   = (unsigned short*)alloc((size_t)N_NODES * HD * 2);   // 25.6 MB
    unsigned* z8A = (unsigned*)alloc((size_t)N_NODES * HD);                   // 12.8 MB
    unsigned* z8B = (unsigned*)alloc((size_t)N_NODES * HD);                   // 12.8 MB
    unsigned short* z3  = (unsigned short*)alloc((size_t)N_NODES * 16 * 2);   // 3.2 MB
    int*   rowptr = (int*)alloc((size_t)(N_NODES + 1) * 4);
    float* invd   = (float*)alloc((size_t)N_NODES * 4);
    int*   eidx   = (int*)alloc((size_t)NE * 4);                              // 6.4 MB
    unsigned* ebuf = (unsigned*)alloc((size_t)NE * 4);                        // 6.4 MB
    int*   cnt    = (int*)alloc((size_t)NB * NBLK * 4);                       // 0.78 MB
    int*   bcnt   = (int*)alloc((size_t)NB * 4);
    int*   boff   = (int*)alloc((size_t)(NB + 1) * 4);
    unsigned short* Wt_fc0 = (unsigned short*)alloc(512 * 128 * 2);
    unsigned short* Wt_fc1 = (unsigned short*)alloc(256 * 128 * 2);
    unsigned short* Wt_g0  = (unsigned short*)alloc(128 * 128 * 2);
    unsigned short* Wt_g1  = (unsigned short*)alloc(128 * 128 * 2);
    unsigned short* Wt_out = (unsigned short*)alloc(128 * 16 * 2);

    // CSR pass A (+ weight prep fused in) — radix partition, zero global atomics
    k_phist_prep<<<NBLK + 70, 256, 0, stream>>>(dst, cnt,
                                                Wfc0, Wt_fc0, Wfc1, Wt_fc1,
                                                Wg0, Wt_g0, Wg1, Wt_g1, Wout, Wt_out);
    k_colscan<<<NB, 64, 0, stream>>>(cnt, bcnt);
    k_bscan<<<1, 64, 0, stream>>>(bcnt, boff, rowptr);
    k_pplace<<<NBLK, 256, 0, stream>>>(src, dst, boff, cnt, ebuf);
    k_bplace<<<NB, 256, 0, stream>>>(ebuf, boff, rowptr, invd, eidx);

    // fused projection + layer-1 GEMM: z1 = (feat @ Wfc + bfc) @ Wg0  (bf16 + fp8)
    k_proj_fused<512><<<512, 512, 0, stream>>>(feat0, Wt_fc0, bfc0, Wt_g0, zA, z8A, N0_ROWS / 16, 0);
    k_proj_fused<256><<<512, 512, 0, stream>>>(feat1, Wt_fc1, bfc1, Wt_g0, zA, z8A, N1_ROWS / 16, N0_ROWS);

    // layer 1 agg: h1 = sigmoid(z1 + mean(z1) + bg0)   [fp8 neighbor gather]
    k_aggz8<<<2048, 256, 0, stream>>>(zA, z8A, rowptr, eidx, invd, bg0, h);
    // layer 2 GEMM: z2 = h1 @ Wg1  (bf16 + fp8)
    k_z_gemm<<<2084, 256, 0, stream>>>(h, Wt_g1, zB, z8B);
    // layer 2 agg: h2 = sigmoid(z2 + mean(z2) + bg1)   [fp8 neighbor gather]
    k_aggz8<<<2048, 256, 0, stream>>>(zB, z8B, rowptr, eidx, invd, bg1, h);
    // layer 3 GEMM: z3 = h2 @ Wout (N x 16, bf16)
    k_zout_gemm<<<1563, 256, 0, stream>>>(h, Wt_out, z3);
    // final aggregation: out = sigmoid(z3 + mean(z3) + bout)
    k_agg16<<<2048, 256, 0, stream>>>(z3, rowptr, eidx, invd, bout, (float*)d_out);
}